// Round 1
// baseline (210.210 us; speedup 1.0000x reference)
//
#include <hip/hip_runtime.h>
#include <math.h>

#define HH 512
#define WW 512
#define NIMG 64
#define NTOT (64u*512u*512u)
#define TS 64
#define LDSW 68
#define NBLK 4096

__device__ __forceinline__ float shrinkf(float x, float l) {
    float a = x - l, b = x + l;
    return x + 0.5f * (__builtin_sqrtf(a * a + 1.f) - __builtin_sqrtf(b * b + 1.f));
}

__device__ __forceinline__ float bf2f(unsigned short u) {
    union { unsigned int i; float f; } cv;
    cv.i = ((unsigned int)u) << 16;
    return cv.f;
}

__device__ __forceinline__ unsigned short f2bf(float f) {
    union { float f; unsigned int i; } cv;
    cv.f = f;
    unsigned int i = cv.i;
    unsigned int r = (i + 0x7fffu + ((i >> 16) & 1u)) >> 16;  // RNE
    return (unsigned short)r;
}

// MODE 0: in = y (fp32), identity transform, out bf16 (t1)
// MODE 1: in = t1 (bf16), transform shrink(n1(t1), l0), out bf16 (t2)
// MODE 2: in = t1,t2 (bf16), transform shrink(n2(t2)+n1(t1), l1), out fp32 (d_out)
template <int MODE>
__global__ __launch_bounds__(256, 2) void conv_bn_k(
    const float* __restrict__ yin,
    const unsigned short* __restrict__ t1,
    const unsigned short* __restrict__ t2,
    unsigned short* __restrict__ outbf,
    float* __restrict__ outf32,
    const float* __restrict__ wgt,
    const float* __restrict__ bias,
    const float* __restrict__ stats,
    const float* __restrict__ lambd,
    double* __restrict__ partials)
{
    __shared__ float tile[LDSW * LDSW];
    __shared__ double rs[256];
    __shared__ double rq[256];

    const int tid = threadIdx.x;
    const int by = blockIdx.y * TS;
    const int bx = blockIdx.x * TS;
    const size_t ibase = (size_t)blockIdx.z * (HH * WW);

    float s1 = 0.f, h1 = 0.f, s2v = 0.f, h2 = 0.f, lam = 0.f;
    if constexpr (MODE == 1) { s1 = stats[0]; h1 = stats[1]; lam = lambd[0]; }
    if constexpr (MODE == 2) {
        s1 = stats[0]; h1 = stats[1]; s2v = stats[2]; h2 = stats[3]; lam = lambd[1];
    }

    for (int idx = tid; idx < LDSW * LDSW; idx += 256) {
        int r = idx / LDSW;
        int c = idx - r * LDSW;
        int gy = by + r - 2, gx = bx + c - 2;
        float v = 0.f;
        if (gy >= 0 && gy < HH && gx >= 0 && gx < WW) {
            size_t g = ibase + (size_t)gy * WW + gx;
            if constexpr (MODE == 0) {
                v = yin[g];
            } else if constexpr (MODE == 1) {
                v = shrinkf(bf2f(t1[g]) * s1 + h1, lam);
            } else {
                v = shrinkf(bf2f(t2[g]) * s2v + h2 + bf2f(t1[g]) * s1 + h1, lam);
            }
        }
        tile[idx] = v;
    }

    // uniform weight/bias loads -> SGPRs
    float w[25];
#pragma unroll
    for (int i = 0; i < 25; i++) w[i] = wgt[i];
    const float b0 = bias[0];

    __syncthreads();

    const int tx = tid & 63;
    const int r0 = (tid >> 6) * 16;  // 16 consecutive output rows per thread

    float acc[16];
#pragma unroll
    for (int i = 0; i < 16; i++) acc[i] = b0;

#pragma unroll
    for (int ir = 0; ir < 20; ir++) {
        const float* rowp = &tile[(r0 + ir) * LDSW + tx];
        float v0 = rowp[0], v1 = rowp[1], v2 = rowp[2], v3 = rowp[3], v4 = rowp[4];
#pragma unroll
        for (int ky = 0; ky < 5; ky++) {
            int o = ir - ky;
            if (o >= 0 && o < 16) {
                acc[o] += w[ky * 5 + 0] * v0 + w[ky * 5 + 1] * v1 + w[ky * 5 + 2] * v2
                        + w[ky * 5 + 3] * v3 + w[ky * 5 + 4] * v4;
            }
        }
    }

    double s = 0.0, q = 0.0;
    size_t obase = ibase + (size_t)(by + r0) * WW + bx + tx;
#pragma unroll
    for (int o = 0; o < 16; o++) {
        float f = acc[o];
        size_t addr = obase + (size_t)o * WW;
        if constexpr (MODE == 2) {
            outf32[addr] = f;
            s += f; q += (double)f * f;
        } else {
            unsigned short hb = f2bf(f);
            outbf[addr] = hb;
            float fr = bf2f(hb);             // stats from stored (rounded) values
            s += fr; q += (double)fr * fr;
        }
    }

    rs[tid] = s; rq[tid] = q;
    __syncthreads();
    for (int off = 128; off > 0; off >>= 1) {
        if (tid < off) { rs[tid] += rs[tid + off]; rq[tid] += rq[tid + off]; }
        __syncthreads();
    }
    if (tid == 0) {
        int bid = (blockIdx.z * 8 + blockIdx.y) * 8 + blockIdx.x;
        partials[bid * 2] = rs[0];
        partials[bid * 2 + 1] = rq[0];
    }
}

__global__ __launch_bounds__(256) void finalize_k(
    const double* __restrict__ partials, float* __restrict__ stats, int stage,
    const float* __restrict__ gamma, const float* __restrict__ beta)
{
    __shared__ double rs[256], rq[256];
    int tid = threadIdx.x;
    double s = 0.0, q = 0.0;
    for (int i = tid; i < NBLK; i += 256) { s += partials[2 * i]; q += partials[2 * i + 1]; }
    rs[tid] = s; rq[tid] = q;
    __syncthreads();
    for (int off = 128; off > 0; off >>= 1) {
        if (tid < off) { rs[tid] += rs[tid + off]; rq[tid] += rq[tid + off]; }
        __syncthreads();
    }
    if (tid == 0) {
        double mean = rs[0] / (double)NTOT;
        double var = rq[0] / (double)NTOT - mean * mean;
        double scl = (double)gamma[0] / sqrt(var + 1e-5);
        stats[2 * stage] = (float)scl;
        stats[2 * stage + 1] = (float)((double)beta[0] - mean * scl);
    }
}

// out = shrink(n3(t3) + n1(t1), lambd[2]); t3 lives in d_out (fp32), in-place.
__global__ __launch_bounds__(256) void final_k(
    const unsigned short* __restrict__ t1, float* __restrict__ io,
    const float* __restrict__ stats, const float* __restrict__ lambd)
{
    const float s1 = stats[0], h1 = stats[1], s3 = stats[4], h3 = stats[5];
    const float lam = lambd[2];
    size_t base = ((size_t)blockIdx.x * 256 + threadIdx.x) * 8;

    uint4 u = *(const uint4*)(t1 + base);          // 8 bf16
    float4 a0 = *(const float4*)(io + base);       // 8 fp32 (t3)
    float4 a1 = *(const float4*)(io + base + 4);

    unsigned short us[8] = {
        (unsigned short)(u.x & 0xffffu), (unsigned short)(u.x >> 16),
        (unsigned short)(u.y & 0xffffu), (unsigned short)(u.y >> 16),
        (unsigned short)(u.z & 0xffffu), (unsigned short)(u.z >> 16),
        (unsigned short)(u.w & 0xffffu), (unsigned short)(u.w >> 16)
    };
    float t3v[8] = { a0.x, a0.y, a0.z, a0.w, a1.x, a1.y, a1.z, a1.w };
    float r[8];
#pragma unroll
    for (int k = 0; k < 8; k++) {
        float v = t3v[k] * s3 + h3 + bf2f(us[k]) * s1 + h1;
        r[k] = shrinkf(v, lam);
    }
    *(float4*)(io + base)     = make_float4(r[0], r[1], r[2], r[3]);
    *(float4*)(io + base + 4) = make_float4(r[4], r[5], r[6], r[7]);
}

extern "C" void kernel_launch(void* const* d_in, const int* in_sizes, int n_in,
                              void* d_out, int out_size, void* d_ws, size_t ws_size,
                              hipStream_t stream)
{
    const float* y     = (const float*)d_in[0];
    const float* wgt   = (const float*)d_in[1];
    const float* bias  = (const float*)d_in[2];
    const float* gamma = (const float*)d_in[3];
    const float* beta  = (const float*)d_in[4];
    const float* lambd = (const float*)d_in[5];
    float* out = (float*)d_out;

    char* ws = (char*)d_ws;
    unsigned short* t1 = (unsigned short*)ws;                    // 33,554,432 B
    unsigned short* t2 = (unsigned short*)(ws + 33554432);       // 33,554,432 B
    double* partials   = (double*)(ws + 67108864);               // 65,536 B
    float* stats       = (float*)(ws + 67174400);                // 24 B

    dim3 grid(8, 8, 64), blk(256);
    conv_bn_k<0><<<grid, blk, 0, stream>>>(y, nullptr, nullptr, t1, nullptr,
                                           wgt, bias, stats, lambd, partials);
    finalize_k<<<1, 256, 0, stream>>>(partials, stats, 0, gamma, beta);
    conv_bn_k<1><<<grid, blk, 0, stream>>>(nullptr, t1, nullptr, t2, nullptr,
                                           wgt, bias, stats, lambd, partials);
    finalize_k<<<1, 256, 0, stream>>>(partials, stats, 1, gamma, beta);
    conv_bn_k<2><<<grid, blk, 0, stream>>>(nullptr, t1, t2, nullptr, out,
                                           wgt, bias, stats, lambd, partials);
    finalize_k<<<1, 256, 0, stream>>>(partials, stats, 2, gamma, beta);
    final_k<<<8192, 256, 0, stream>>>(t1, out, stats, lambd);
}

// Round 2
// 151.879 us; speedup vs baseline: 1.3841x; 1.3841x over previous
//
#include <hip/hip_runtime.h>
#include <math.h>

#define HH 512
#define WW 512
#define NTOT (64u*512u*512u)
#define TS 64
#define TROWS 68
#define TPITCH 72
#define NBLK 4096

__device__ __forceinline__ float fsqrtf(float x) { return __builtin_amdgcn_sqrtf(x); }

__device__ __forceinline__ float shrinkf(float x, float l) {
    float a = x - l, b = x + l;
    return x + 0.5f * (fsqrtf(__builtin_fmaf(a, a, 1.f)) - fsqrtf(__builtin_fmaf(b, b, 1.f)));
}

__device__ __forceinline__ float bf2f(unsigned int u) {
    union { unsigned int i; float f; } cv;
    cv.i = u << 16;
    return cv.f;
}

__device__ __forceinline__ unsigned short f2bf(float f) {
    union { float f; unsigned int i; } cv;
    cv.f = f;
    unsigned int i = cv.i;
    unsigned int r = (i + 0x7fffu + ((i >> 16) & 1u)) >> 16;  // RNE
    return (unsigned short)r;
}

// unpack uint4 (8 bf16) -> 8 floats
__device__ __forceinline__ void bf8(uint4 u, float* f) {
    f[0] = bf2f(u.x & 0xffffu); f[1] = bf2f(u.x >> 16);
    f[2] = bf2f(u.y & 0xffffu); f[3] = bf2f(u.y >> 16);
    f[4] = bf2f(u.z & 0xffffu); f[5] = bf2f(u.z >> 16);
    f[6] = bf2f(u.w & 0xffffu); f[7] = bf2f(u.w >> 16);
}

// MODE 0: in = y (fp32), identity transform          -> t1 (bf16)
// MODE 1: in = t1,  transform shrink(n1(t1), l0)     -> t2 (bf16)
// MODE 2: in = t1,t2, shrink(n2(t2)+n1(t1), l1)      -> t3 (bf16 if OBF else fp32)
template <int MODE, bool OBF>
__global__ __launch_bounds__(256, 4) void conv_bn_k(
    const float* __restrict__ yin,
    const unsigned short* __restrict__ t1,
    const unsigned short* __restrict__ t2,
    unsigned short* __restrict__ outbf,
    float* __restrict__ outf32,
    const float* __restrict__ wgt,
    const float* __restrict__ bias,
    const float* __restrict__ stats,
    const float* __restrict__ lambd,
    float* __restrict__ partials)
{
    __shared__ float tile[TROWS][TPITCH];

    const int tid = threadIdx.x;
    const int by = blockIdx.y * TS;
    const int bx = blockIdx.x * TS;
    const size_t ibase = (size_t)blockIdx.z * (HH * WW);

    float s1 = 0.f, h1 = 0.f, s2v = 0.f, h2 = 0.f, lam = 0.f;
    if constexpr (MODE == 1) { s1 = stats[0]; h1 = stats[1]; lam = lambd[0]; }
    if constexpr (MODE == 2) {
        s1 = stats[0]; h1 = stats[1]; s2v = stats[2]; h2 = stats[3]; lam = lambd[1];
    }

    // ---- vectorized interior staging: 68 rows x 4 segments of 16 cols ----
    for (int i = tid; i < TROWS * 4; i += 256) {
        const int row = i >> 2, seg = i & 3;
        const int gy = by + row - 2;
        float vals[16];
        if (gy >= 0 && gy < HH) {
            const size_t g = ibase + (size_t)gy * WW + bx + seg * 16;
            if constexpr (MODE == 0) {
                const float4* p = (const float4*)(yin + g);
                float4 a = p[0], b = p[1], c = p[2], d = p[3];
                vals[0]=a.x; vals[1]=a.y; vals[2]=a.z; vals[3]=a.w;
                vals[4]=b.x; vals[5]=b.y; vals[6]=b.z; vals[7]=b.w;
                vals[8]=c.x; vals[9]=c.y; vals[10]=c.z; vals[11]=c.w;
                vals[12]=d.x; vals[13]=d.y; vals[14]=d.z; vals[15]=d.w;
            } else if constexpr (MODE == 1) {
                const uint4* p = (const uint4*)(t1 + g);
                uint4 ua = p[0], ub = p[1];
                float f[16]; bf8(ua, f); bf8(ub, f + 8);
#pragma unroll
                for (int k = 0; k < 16; k++)
                    vals[k] = shrinkf(__builtin_fmaf(f[k], s1, h1), lam);
            } else {
                const uint4* p1 = (const uint4*)(t1 + g);
                const uint4* p2 = (const uint4*)(t2 + g);
                uint4 a1 = p1[0], b1 = p1[1], a2 = p2[0], b2 = p2[1];
                float f1[16], f2[16];
                bf8(a1, f1); bf8(b1, f1 + 8); bf8(a2, f2); bf8(b2, f2 + 8);
#pragma unroll
                for (int k = 0; k < 16; k++) {
                    float v = __builtin_fmaf(f2[k], s2v, h2)
                            + __builtin_fmaf(f1[k], s1, h1);
                    vals[k] = shrinkf(v, lam);
                }
            }
        } else {
#pragma unroll
            for (int k = 0; k < 16; k++) vals[k] = 0.f;
        }
        float4* tp = (float4*)&tile[row][4 + seg * 16];
        tp[0] = make_float4(vals[0], vals[1], vals[2], vals[3]);
        tp[1] = make_float4(vals[4], vals[5], vals[6], vals[7]);
        tp[2] = make_float4(vals[8], vals[9], vals[10], vals[11]);
        tp[3] = make_float4(vals[12], vals[13], vals[14], vals[15]);
    }

    // ---- halo cols: c in {2,3,68,69} <-> gx in {bx-2,bx-1,bx+64,bx+65} ----
    for (int j = tid; j < TROWS * 4; j += 256) {
        const int row = j >> 2, side = j & 3;
        const int c = (side < 2) ? (2 + side) : (66 + side);
        const int gx = bx + c - 4;
        const int gy = by + row - 2;
        float v = 0.f;
        if (gy >= 0 && gy < HH && gx >= 0 && gx < WW) {
            const size_t g = ibase + (size_t)gy * WW + gx;
            if constexpr (MODE == 0) {
                v = yin[g];
            } else if constexpr (MODE == 1) {
                v = shrinkf(__builtin_fmaf(bf2f(t1[g]), s1, h1), lam);
            } else {
                float vv = __builtin_fmaf(bf2f(t2[g]), s2v, h2)
                         + __builtin_fmaf(bf2f(t1[g]), s1, h1);
                v = shrinkf(vv, lam);
            }
        }
        tile[row][c] = v;
    }

    float w[25];
#pragma unroll
    for (int i = 0; i < 25; i++) w[i] = wgt[i];
    const float b0 = bias[0];

    __syncthreads();

    const int tx = tid & 63;
    const int r0 = (tid >> 6) * 16;  // 16 consecutive output rows per thread

    float acc[16];
#pragma unroll
    for (int i = 0; i < 16; i++) acc[i] = b0;

#pragma unroll
    for (int ir = 0; ir < 20; ir++) {
        const float* rowp = &tile[r0 + ir][tx + 2];
        float v0 = rowp[0], v1 = rowp[1], v2 = rowp[2], v3 = rowp[3], v4 = rowp[4];
#pragma unroll
        for (int ky = 0; ky < 5; ky++) {
            const int o = ir - ky;
            if (o >= 0 && o < 16) {
                acc[o] += w[ky * 5 + 0] * v0 + w[ky * 5 + 1] * v1 + w[ky * 5 + 2] * v2
                        + w[ky * 5 + 3] * v3 + w[ky * 5 + 4] * v4;
            }
        }
    }

    float s = 0.f, q = 0.f;
    const size_t obase = ibase + (size_t)(by + r0) * WW + bx + tx;
#pragma unroll
    for (int o = 0; o < 16; o++) {
        float f = acc[o];
        const size_t addr = obase + (size_t)o * WW;
        if constexpr (OBF) {
            unsigned short hb = f2bf(f);
            outbf[addr] = hb;
            float fr = bf2f(hb);
            s += fr; q = __builtin_fmaf(fr, fr, q);
        } else {
            outf32[addr] = f;
            s += f; q = __builtin_fmaf(f, f, q);
        }
    }

    // block reduction, f32, aliased into the (now dead) tile
    __syncthreads();
    float* red = &tile[0][0];
    red[tid] = s; red[256 + tid] = q;
    __syncthreads();
    for (int off = 128; off > 0; off >>= 1) {
        if (tid < off) { red[tid] += red[tid + off]; red[256 + tid] += red[256 + tid + off]; }
        __syncthreads();
    }
    if (tid == 0) {
        const int bid = (blockIdx.z * 8 + blockIdx.y) * 8 + blockIdx.x;
        partials[bid * 2] = red[0];
        partials[bid * 2 + 1] = red[256];
    }
}

__global__ __launch_bounds__(256) void finalize_k(
    const float* __restrict__ partials, float* __restrict__ stats, int stage,
    const float* __restrict__ gamma, const float* __restrict__ beta)
{
    __shared__ double rs[256], rq[256];
    const int tid = threadIdx.x;
    double s = 0.0, q = 0.0;
    for (int i = tid; i < NBLK; i += 256) { s += partials[2 * i]; q += partials[2 * i + 1]; }
    rs[tid] = s; rq[tid] = q;
    __syncthreads();
    for (int off = 128; off > 0; off >>= 1) {
        if (tid < off) { rs[tid] += rs[tid + off]; rq[tid] += rq[tid + off]; }
        __syncthreads();
    }
    if (tid == 0) {
        double mean = rs[0] / (double)NTOT;
        double var = rq[0] / (double)NTOT - mean * mean;
        double scl = (double)gamma[0] / sqrt(var + 1e-5);
        stats[2 * stage] = (float)scl;
        stats[2 * stage + 1] = (float)((double)beta[0] - mean * scl);
    }
}

// out = shrink(n3(t3) + n1(t1), lambd[2])
template <bool T3BF>
__global__ __launch_bounds__(256) void final_k(
    const unsigned short* __restrict__ t1,
    const unsigned short* __restrict__ t3b,
    float* __restrict__ io,
    const float* __restrict__ stats, const float* __restrict__ lambd)
{
    const float s1 = stats[0], h1 = stats[1], s3 = stats[4], h3 = stats[5];
    const float lam = lambd[2];
    const size_t base = ((size_t)blockIdx.x * 256 + threadIdx.x) * 8;

    uint4 u1 = *(const uint4*)(t1 + base);
    float f1[8]; bf8(u1, f1);

    float t3v[8];
    if constexpr (T3BF) {
        uint4 u3 = *(const uint4*)(t3b + base);
        bf8(u3, t3v);
    } else {
        float4 a0 = *(const float4*)(io + base);
        float4 a1 = *(const float4*)(io + base + 4);
        t3v[0]=a0.x; t3v[1]=a0.y; t3v[2]=a0.z; t3v[3]=a0.w;
        t3v[4]=a1.x; t3v[5]=a1.y; t3v[6]=a1.z; t3v[7]=a1.w;
    }

    float r[8];
#pragma unroll
    for (int k = 0; k < 8; k++) {
        float v = __builtin_fmaf(t3v[k], s3, h3) + __builtin_fmaf(f1[k], s1, h1);
        r[k] = shrinkf(v, lam);
    }
    *(float4*)(io + base)     = make_float4(r[0], r[1], r[2], r[3]);
    *(float4*)(io + base + 4) = make_float4(r[4], r[5], r[6], r[7]);
}

extern "C" void kernel_launch(void* const* d_in, const int* in_sizes, int n_in,
                              void* d_out, int out_size, void* d_ws, size_t ws_size,
                              hipStream_t stream)
{
    const float* y     = (const float*)d_in[0];
    const float* wgt   = (const float*)d_in[1];
    const float* bias  = (const float*)d_in[2];
    const float* gamma = (const float*)d_in[3];
    const float* beta  = (const float*)d_in[4];
    const float* lambd = (const float*)d_in[5];
    float* out = (float*)d_out;

    char* ws = (char*)d_ws;
    unsigned short* t1 = (unsigned short*)ws;                       // 33,554,432 B
    unsigned short* t2 = (unsigned short*)(ws + 33554432ull);       // 33,554,432 B
    unsigned short* t3 = (unsigned short*)(ws + 67108864ull);       // 33,554,432 B
    const bool t3bf = (ws_size >= 100696088ull);
    size_t poff = t3bf ? 100663296ull : 67108864ull;
    float* partials = (float*)(ws + poff);                          // 32,768 B
    float* stats    = (float*)(ws + poff + 32768ull);               // 24 B

    dim3 grid(8, 8, 64), blk(256);
    conv_bn_k<0, true><<<grid, blk, 0, stream>>>(y, nullptr, nullptr, t1, nullptr,
                                                 wgt, bias, stats, lambd, partials);
    finalize_k<<<1, 256, 0, stream>>>(partials, stats, 0, gamma, beta);
    conv_bn_k<1, true><<<grid, blk, 0, stream>>>(nullptr, t1, nullptr, t2, nullptr,
                                                 wgt, bias, stats, lambd, partials);
    finalize_k<<<1, 256, 0, stream>>>(partials, stats, 1, gamma, beta);
    if (t3bf) {
        conv_bn_k<2, true><<<grid, blk, 0, stream>>>(nullptr, t1, t2, t3, nullptr,
                                                     wgt, bias, stats, lambd, partials);
        finalize_k<<<1, 256, 0, stream>>>(partials, stats, 2, gamma, beta);
        final_k<true><<<8192, 256, 0, stream>>>(t1, t3, out, stats, lambd);
    } else {
        conv_bn_k<2, false><<<grid, blk, 0, stream>>>(nullptr, t1, t2, nullptr, out,
                                                      wgt, bias, stats, lambd, partials);
        finalize_k<<<1, 256, 0, stream>>>(partials, stats, 2, gamma, beta);
        final_k<false><<<8192, 256, 0, stream>>>(t1, nullptr, out, stats, lambd);
    }
}

// Round 4
// 147.709 us; speedup vs baseline: 1.4231x; 1.0282x over previous
//
#include <hip/hip_runtime.h>
#include <math.h>

#define HH 512
#define WW 512
#define NTOT (64u*512u*512u)
#define NBLK 4096
#define TP 84   // LDS tile pitch (floats); tile col c <-> gx = bx + c - 8

__device__ __forceinline__ float fsqrtf(float x) { return __builtin_amdgcn_sqrtf(x); }

__device__ __forceinline__ float shrinkf(float x, float l) {
    float a = x - l, b = x + l;
    return x + 0.5f * (fsqrtf(__builtin_fmaf(a, a, 1.f)) - fsqrtf(__builtin_fmaf(b, b, 1.f)));
}

__device__ __forceinline__ float bf2f(unsigned int u) {
    union { unsigned int i; float f; } cv;
    cv.i = u << 16;
    return cv.f;
}

__device__ __forceinline__ unsigned short f2bf(float f) {
    union { float f; unsigned int i; } cv;
    cv.f = f;
    unsigned int i = cv.i;
    unsigned int r = (i + 0x7fffu + ((i >> 16) & 1u)) >> 16;  // RNE
    return (unsigned short)r;
}

__device__ __forceinline__ void bf8(uint4 u, float* f) {
    f[0] = bf2f(u.x & 0xffffu); f[1] = bf2f(u.x >> 16);
    f[2] = bf2f(u.y & 0xffffu); f[3] = bf2f(u.y >> 16);
    f[4] = bf2f(u.z & 0xffffu); f[5] = bf2f(u.z >> 16);
    f[6] = bf2f(u.w & 0xffffu); f[7] = bf2f(u.w >> 16);
}

// MODE 0: in = y (fp32), identity transform            -> t1 (bf16)
// MODE 1: in = t1, transform shrink(n1(t1), l0)        -> t2 (bf16)
// MODE 2: in = t1,t2, shrink(n2(t2)+n1(t1), l1)        -> t3 bf16 (OBF) / fp32 (!OBF)
// All buffers COMPACT [64][512][512]. OOB conv-input positions are ZERO
// (post-transform zero, matching the reference's conv zero-padding).
template <int MODE, bool OBF>
__global__ __launch_bounds__(256, 7) void conv_k(
    const float* __restrict__ yin,
    const unsigned short* __restrict__ t1,
    const unsigned short* __restrict__ t2,
    unsigned short* __restrict__ outbf,
    float* __restrict__ outf32,
    const float* __restrict__ wgt,
    const float* __restrict__ bias,
    const float* __restrict__ stats,
    const float* __restrict__ lambd,
    float* __restrict__ partials)
{
    __shared__ float tile[68][TP];

    const int tid = threadIdx.x;
    const int by = blockIdx.y * 64;
    const int bx = blockIdx.x * 64;
    const size_t ibase = (size_t)blockIdx.z * (HH * WW);

    float s1 = 0.f, h1 = 0.f, s2v = 0.f, h2 = 0.f, lam = 0.f;
    if constexpr (MODE == 1) { s1 = stats[0]; h1 = stats[1]; lam = lambd[0]; }
    if constexpr (MODE == 2) {
        s1 = stats[0]; h1 = stats[1]; s2v = stats[2]; h2 = stats[3]; lam = lambd[1];
    }

    // ---- unified chunked staging: 68 rows x 10 chunks of 8 = 680 tasks ----
    // chunk ch covers gx0 = bx + ch*8 - 8 .. +7.  Image-border chunks are
    // exactly whole tasks (gx0 < 0 only at bx=0,ch=0; gx0 >= 512 only at
    // bx=448,ch=9; gy OOB only rows 0,1 / 66,67) -> uniform predicate.
    for (int i = tid; i < 680; i += 256) {
        const int row = i / 10;
        const int ch = i - row * 10;
        const int gy = by + row - 2;
        const int gx0 = bx + ch * 8 - 8;
        float vals[8];
        if (gy >= 0 && gy < HH && gx0 >= 0 && gx0 < WW) {
            const size_t g = ibase + (size_t)gy * WW + gx0;
            if constexpr (MODE == 0) {
                const float4* p = (const float4*)(yin + g);
                float4 a = p[0], b = p[1];
                vals[0]=a.x; vals[1]=a.y; vals[2]=a.z; vals[3]=a.w;
                vals[4]=b.x; vals[5]=b.y; vals[6]=b.z; vals[7]=b.w;
            } else if constexpr (MODE == 1) {
                uint4 u1 = *(const uint4*)(t1 + g);
                float f1[8]; bf8(u1, f1);
#pragma unroll
                for (int k = 0; k < 8; k++)
                    vals[k] = shrinkf(__builtin_fmaf(f1[k], s1, h1), lam);
            } else {
                uint4 u1 = *(const uint4*)(t1 + g);
                uint4 u2 = *(const uint4*)(t2 + g);
                float f1[8], f2[8]; bf8(u1, f1); bf8(u2, f2);
#pragma unroll
                for (int k = 0; k < 8; k++) {
                    float v = __builtin_fmaf(f2[k], s2v, h2)
                            + __builtin_fmaf(f1[k], s1, h1);
                    vals[k] = shrinkf(v, lam);
                }
            }
        } else {
#pragma unroll
            for (int k = 0; k < 8; k++) vals[k] = 0.f;
        }
        float4* tp = (float4*)&tile[row][ch * 8];
        tp[0] = make_float4(vals[0], vals[1], vals[2], vals[3]);
        tp[1] = make_float4(vals[4], vals[5], vals[6], vals[7]);
    }

    float w[25];
#pragma unroll
    for (int i = 0; i < 25; i++) w[i] = wgt[i];
    const float b0 = bias[0];

    __syncthreads();

    const int tx = tid & 63;
    const int r0 = (tid >> 6) * 16;   // wave-uniform: 16 consecutive rows/thread

    float acc[16];
#pragma unroll
    for (int i = 0; i < 16; i++) acc[i] = b0;

#pragma unroll
    for (int ir = 0; ir < 20; ir++) {
        const float* rowp = &tile[r0 + ir][tx + 6];   // gx-2 .. gx+2
        float v0 = rowp[0], v1 = rowp[1], v2 = rowp[2], v3 = rowp[3], v4 = rowp[4];
#pragma unroll
        for (int ky = 0; ky < 5; ky++) {
            const int o = ir - ky;
            if (o >= 0 && o < 16) {
                acc[o] += w[ky * 5 + 0] * v0 + w[ky * 5 + 1] * v1 + w[ky * 5 + 2] * v2
                        + w[ky * 5 + 3] * v3 + w[ky * 5 + 4] * v4;
            }
        }
    }

    float s = 0.f, q = 0.f;
    const size_t obase = ibase + (size_t)(by + r0) * WW + bx + tx;
#pragma unroll
    for (int o = 0; o < 16; o++) {
        float f = acc[o];
        const size_t addr = obase + (size_t)o * WW;
        if constexpr (OBF) {
            unsigned short hb = f2bf(f);
            outbf[addr] = hb;
            float fr = bf2f(hb);                 // stats from stored values
            s += fr; q = __builtin_fmaf(fr, fr, q);
        } else {
            outf32[addr] = f;
            s += f; q = __builtin_fmaf(f, f, q);
        }
    }

    __syncthreads();
    float* red = &tile[0][0];
    red[tid] = s; red[256 + tid] = q;
    __syncthreads();
    for (int off = 128; off > 0; off >>= 1) {
        if (tid < off) { red[tid] += red[tid + off]; red[256 + tid] += red[256 + tid + off]; }
        __syncthreads();
    }
    if (tid == 0) {
        const int bid = (blockIdx.z * 8 + blockIdx.y) * 8 + blockIdx.x;
        partials[bid * 2] = red[0];
        partials[bid * 2 + 1] = red[256];
    }
}

__global__ __launch_bounds__(256) void finalize_k(
    const float* __restrict__ partials, float* __restrict__ stats, int stage,
    const float* __restrict__ gamma, const float* __restrict__ beta)
{
    __shared__ double rs[256], rq[256];
    const int tid = threadIdx.x;
    double s = 0.0, q = 0.0;
    for (int i = tid; i < NBLK; i += 256) { s += partials[2 * i]; q += partials[2 * i + 1]; }
    rs[tid] = s; rq[tid] = q;
    __syncthreads();
    for (int off = 128; off > 0; off >>= 1) {
        if (tid < off) { rs[tid] += rs[tid + off]; rq[tid] += rq[tid + off]; }
        __syncthreads();
    }
    if (tid == 0) {
        double mean = rs[0] / (double)NTOT;
        double var = rq[0] / (double)NTOT - mean * mean;
        double scl = (double)gamma[0] / sqrt(var + 1e-5);
        stats[2 * stage] = (float)scl;
        stats[2 * stage + 1] = (float)((double)beta[0] - mean * scl);
    }
}

// out = shrink(n3(t3) + n1(t1), lambd[2]); t3 bf16 (T3BF) or fp32 in io
template <bool T3BF>
__global__ __launch_bounds__(256) void final_k(
    const unsigned short* __restrict__ t1,
    const unsigned short* __restrict__ t3b,
    float* __restrict__ io,
    const float* __restrict__ stats, const float* __restrict__ lambd)
{
    const float s1 = stats[0], h1 = stats[1], s3 = stats[4], h3 = stats[5];
    const float lam = lambd[2];
    const size_t base = ((size_t)blockIdx.x * 256 + threadIdx.x) * 8;

    uint4 u1 = *(const uint4*)(t1 + base);
    float f1[8]; bf8(u1, f1);

    float t3v[8];
    if constexpr (T3BF) {
        uint4 u3 = *(const uint4*)(t3b + base);
        bf8(u3, t3v);
    } else {
        float4 a0 = *(const float4*)(io + base);
        float4 a1 = *(const float4*)(io + base + 4);
        t3v[0]=a0.x; t3v[1]=a0.y; t3v[2]=a0.z; t3v[3]=a0.w;
        t3v[4]=a1.x; t3v[5]=a1.y; t3v[6]=a1.z; t3v[7]=a1.w;
    }

    float r[8];
#pragma unroll
    for (int k = 0; k < 8; k++) {
        float v = __builtin_fmaf(t3v[k], s3, h3) + __builtin_fmaf(f1[k], s1, h1);
        r[k] = shrinkf(v, lam);
    }
    *(float4*)(io + base)     = make_float4(r[0], r[1], r[2], r[3]);
    *(float4*)(io + base + 4) = make_float4(r[4], r[5], r[6], r[7]);
}

extern "C" void kernel_launch(void* const* d_in, const int* in_sizes, int n_in,
                              void* d_out, int out_size, void* d_ws, size_t ws_size,
                              hipStream_t stream)
{
    const float* y     = (const float*)d_in[0];
    const float* wgt   = (const float*)d_in[1];
    const float* bias  = (const float*)d_in[2];
    const float* gamma = (const float*)d_in[3];
    const float* beta  = (const float*)d_in[4];
    const float* lambd = (const float*)d_in[5];
    float* out = (float*)d_out;

    char* ws = (char*)d_ws;
    unsigned short* t1 = (unsigned short*)ws;                    // 33,554,432 B
    unsigned short* t2 = (unsigned short*)(ws + 33554432ull);    // 33,554,432 B
    unsigned short* t3 = (unsigned short*)(ws + 67108864ull);    // 33,554,432 B
    const bool t3bf = (ws_size >= 100696088ull);
    const size_t poff = t3bf ? 100663296ull : 67108864ull;
    float* partials = (float*)(ws + poff);                       // 32,768 B
    float* stats    = (float*)(ws + poff + 32768ull);            // 24 B

    dim3 grid(8, 8, 64), blk(256);
    conv_k<0, true><<<grid, blk, 0, stream>>>(y, nullptr, nullptr, t1, nullptr,
                                              wgt, bias, stats, lambd, partials);
    finalize_k<<<1, blk, 0, stream>>>(partials, stats, 0, gamma, beta);
    conv_k<1, true><<<grid, blk, 0, stream>>>(nullptr, t1, nullptr, t2, nullptr,
                                              wgt, bias, stats, lambd, partials);
    finalize_k<<<1, blk, 0, stream>>>(partials, stats, 1, gamma, beta);
    if (t3bf) {
        conv_k<2, true><<<grid, blk, 0, stream>>>(nullptr, t1, t2, t3, nullptr,
                                                  wgt, bias, stats, lambd, partials);
        finalize_k<<<1, blk, 0, stream>>>(partials, stats, 2, gamma, beta);
        final_k<true><<<8192, blk, 0, stream>>>(t1, t3, out, stats, lambd);
    } else {
        conv_k<2, false><<<grid, blk, 0, stream>>>(nullptr, t1, t2, nullptr, out,
                                                   wgt, bias, stats, lambd, partials);
        finalize_k<<<1, blk, 0, stream>>>(partials, stats, 2, gamma, beta);
        final_k<false><<<8192, blk, 0, stream>>>(t1, nullptr, out, stats, lambd);
    }
}

// Round 5
// 135.184 us; speedup vs baseline: 1.5550x; 1.0926x over previous
//
#include <hip/hip_runtime.h>
#include <math.h>

#define HH 512
#define WW 512
#define NTOT (64u*512u*512u)
#define NBLK 4096
#define TPIT 88   // LDS tile pitch in bf16 elems; tile col t <-> gx = bx + t - 8

typedef __attribute__((ext_vector_type(8))) short short8;
typedef __attribute__((ext_vector_type(4))) float f32x4;

__device__ __forceinline__ float fsqrtf(float x) { return __builtin_amdgcn_sqrtf(x); }

__device__ __forceinline__ float shrinkf(float x, float l) {
    float a = x - l, b = x + l;
    return x + 0.5f * (fsqrtf(__builtin_fmaf(a, a, 1.f)) - fsqrtf(__builtin_fmaf(b, b, 1.f)));
}

__device__ __forceinline__ float bf2f(unsigned int u) {
    union { unsigned int i; float f; } cv;
    cv.i = u << 16;
    return cv.f;
}

__device__ __forceinline__ float lo2f(unsigned int p) {
    union { unsigned int i; float f; } cv; cv.i = p << 16; return cv.f;
}
__device__ __forceinline__ float hi2f(unsigned int p) {
    union { unsigned int i; float f; } cv; cv.i = p & 0xffff0000u; return cv.f;
}

__device__ __forceinline__ unsigned short f2bf(float f) {
    union { float f; unsigned int i; } cv;
    cv.f = f;
    unsigned int i = cv.i;
    unsigned int r = (i + 0x7fffu + ((i >> 16) & 1u)) >> 16;  // RNE
    return (unsigned short)r;
}

// v_cvt_pk_bf16_f32: dst = bf16(lo) | (bf16(hi) << 16)
__device__ __forceinline__ unsigned int cvtpk(float lo, float hi) {
    unsigned int r;
    asm("v_cvt_pk_bf16_f32 %0, %1, %2" : "=v"(r) : "v"(lo), "v"(hi));
    return r;
}

__device__ __forceinline__ void bf8(uint4 u, float* f) {
    f[0] = bf2f(u.x & 0xffffu); f[1] = bf2f(u.x >> 16);
    f[2] = bf2f(u.y & 0xffffu); f[3] = bf2f(u.y >> 16);
    f[4] = bf2f(u.z & 0xffffu); f[5] = bf2f(u.z >> 16);
    f[6] = bf2f(u.w & 0xffffu); f[7] = bf2f(u.w >> 16);
}

// MFMA conv: out[r][c] = sum_ky A_ky x B_ky with
//   A_ky[m][k] = tile[r0+m+ky][c0+k]  (tile col t <-> gx = bx + t - 8)
//   B_ky[k][n] = w[ky][k-n-6] if 0 <= k-n-6 <= 4 else 0
// MODE 0: in y (fp32) identity -> t1 bf16
// MODE 1: in t1, shrink(n1(t1), l0) -> t2 bf16
// MODE 2: in t1,t2, shrink(n2+n1, l1) -> t3 bf16 (OBF) / fp32 (!OBF)
template <int MODE, bool OBF>
__global__ __launch_bounds__(256, 6) void conv_k(
    const float* __restrict__ yin,
    const unsigned short* __restrict__ t1,
    const unsigned short* __restrict__ t2,
    unsigned short* __restrict__ outbf,
    float* __restrict__ outf32,
    const float* __restrict__ wgt,
    const float* __restrict__ bias,
    const float* __restrict__ stats,
    const float* __restrict__ lambd,
    float* __restrict__ partials)
{
    __shared__ unsigned short tile[68 * TPIT];
    __shared__ uint4 btab[5 * 64];

    const int tid = threadIdx.x;
    const int by = blockIdx.y * 64;
    const int bx = blockIdx.x * 64;
    const size_t ibase = (size_t)blockIdx.z * (HH * WW);

    float s1 = 0.f, h1 = 0.f, s2v = 0.f, h2 = 0.f, lam = 0.f;
    if constexpr (MODE == 1) { s1 = stats[0]; h1 = stats[1]; lam = lambd[0]; }
    if constexpr (MODE == 2) {
        s1 = stats[0]; h1 = stats[1]; s2v = stats[2]; h2 = stats[3]; lam = lambd[1];
    }

    // ---- B-fragment table (wave 0): lane holds B[k=(l>>4)*8+j][n=l&15] ----
    if (tid < 64) {
        float wv[25];
#pragma unroll
        for (int i = 0; i < 25; i++) wv[i] = wgt[i];
        const int sPos = (tid & 15) + 6 - (tid >> 4) * 8;   // j = sPos + kx
#pragma unroll
        for (int ky = 0; ky < 5; ky++) {
            unsigned short ev[8];
#pragma unroll
            for (int j = 0; j < 8; j++) {
                float v = 0.f;
#pragma unroll
                for (int t = 0; t < 5; t++)
                    if (j - sPos == t) v = wv[ky * 5 + t];
                ev[j] = f2bf(v);
            }
            btab[ky * 64 + tid] = make_uint4(
                ev[0] | ((unsigned)ev[1] << 16), ev[2] | ((unsigned)ev[3] << 16),
                ev[4] | ((unsigned)ev[5] << 16), ev[6] | ((unsigned)ev[7] << 16));
        }
    }

    // ---- staging: 68 rows x 10 chunks of 8 bf16; all loads/stores 16B-aligned
    for (int i = tid; i < 680; i += 256) {
        const int row = i / 10;
        const int ch = i - row * 10;
        const int gy = by + row - 2;
        const int gx0 = bx + ch * 8 - 8;       // full chunk in/out of image
        uint4 pk = make_uint4(0u, 0u, 0u, 0u);
        if (gy >= 0 && gy < HH && gx0 >= 0 && gx0 + 8 <= WW) {
            const size_t g = ibase + (size_t)gy * WW + gx0;
            if constexpr (MODE == 0) {
                const float4* p = (const float4*)(yin + g);
                float4 a = p[0], b = p[1];
                pk.x = cvtpk(a.x, a.y); pk.y = cvtpk(a.z, a.w);
                pk.z = cvtpk(b.x, b.y); pk.w = cvtpk(b.z, b.w);
            } else if constexpr (MODE == 1) {
                uint4 u1 = *(const uint4*)(t1 + g);
                float f1[8]; bf8(u1, f1);
                float v[8];
#pragma unroll
                for (int k = 0; k < 8; k++)
                    v[k] = shrinkf(__builtin_fmaf(f1[k], s1, h1), lam);
                pk.x = cvtpk(v[0], v[1]); pk.y = cvtpk(v[2], v[3]);
                pk.z = cvtpk(v[4], v[5]); pk.w = cvtpk(v[6], v[7]);
            } else {
                uint4 u1 = *(const uint4*)(t1 + g);
                uint4 u2 = *(const uint4*)(t2 + g);
                float f1[8], f2[8]; bf8(u1, f1); bf8(u2, f2);
                float v[8];
#pragma unroll
                for (int k = 0; k < 8; k++) {
                    float x = __builtin_fmaf(f2[k], s2v, h2)
                            + __builtin_fmaf(f1[k], s1, h1);
                    v[k] = shrinkf(x, lam);
                }
                pk.x = cvtpk(v[0], v[1]); pk.y = cvtpk(v[2], v[3]);
                pk.z = cvtpk(v[4], v[5]); pk.w = cvtpk(v[6], v[7]);
            }
        }
        *(uint4*)&tile[row * TPIT + ch * 8] = pk;
    }

    const float b0 = bias[0];
    __syncthreads();

    const int lane = tid & 63;
    const int lm = lane & 15;
    const int kb = lane >> 4;
    const int r0 = (tid >> 6) * 16;   // wave's 16 output rows

    f32x4 acc0 = {0.f, 0.f, 0.f, 0.f};
    f32x4 acc1 = acc0, acc2 = acc0, acc3 = acc0;
    const unsigned short* abase = &tile[(r0 + lm) * TPIT + kb * 8];

#pragma unroll
    for (int ky = 0; ky < 5; ky++) {
        const short8 bfr = *(const short8*)&btab[ky * 64 + lane];
        short8 a0 = *(const short8*)(abase + ky * TPIT);
        short8 a1 = *(const short8*)(abase + ky * TPIT + 16);
        short8 a2 = *(const short8*)(abase + ky * TPIT + 32);
        short8 a3 = *(const short8*)(abase + ky * TPIT + 48);
        acc0 = __builtin_amdgcn_mfma_f32_16x16x32_bf16(a0, bfr, acc0, 0, 0, 0);
        acc1 = __builtin_amdgcn_mfma_f32_16x16x32_bf16(a1, bfr, acc1, 0, 0, 0);
        acc2 = __builtin_amdgcn_mfma_f32_16x16x32_bf16(a2, bfr, acc2, 0, 0, 0);
        acc3 = __builtin_amdgcn_mfma_f32_16x16x32_bf16(a3, bfr, acc3, 0, 0, 0);
    }

    // ---- epilogue: C/D lane holds rows kb*4+e, col lm (per 16x16 tile ct) ----
    float s = 0.f, q = 0.f;
    const int grow0 = by + r0 + kb * 4;

    auto emit = [&](const f32x4& a, int ct) {
        const size_t base = ibase + (size_t)grow0 * WW + bx + ct * 16 + lm;
        if constexpr (OBF) {
            unsigned p01 = cvtpk(a[0] + b0, a[1] + b0);
            unsigned p23 = cvtpk(a[2] + b0, a[3] + b0);
            outbf[base]          = (unsigned short)(p01 & 0xffffu);
            outbf[base + WW]     = (unsigned short)(p01 >> 16);
            outbf[base + 2 * WW] = (unsigned short)(p23 & 0xffffu);
            outbf[base + 3 * WW] = (unsigned short)(p23 >> 16);
            float fr0 = lo2f(p01), fr1 = hi2f(p01), fr2 = lo2f(p23), fr3 = hi2f(p23);
            s += fr0 + fr1 + fr2 + fr3;
            q = __builtin_fmaf(fr0, fr0, __builtin_fmaf(fr1, fr1,
                __builtin_fmaf(fr2, fr2, __builtin_fmaf(fr3, fr3, q))));
        } else {
            float f0 = a[0] + b0, f1 = a[1] + b0, f2 = a[2] + b0, f3 = a[3] + b0;
            outf32[base]          = f0;
            outf32[base + WW]     = f1;
            outf32[base + 2 * WW] = f2;
            outf32[base + 3 * WW] = f3;
            s += f0 + f1 + f2 + f3;
            q = __builtin_fmaf(f0, f0, __builtin_fmaf(f1, f1,
                __builtin_fmaf(f2, f2, __builtin_fmaf(f3, f3, q))));
        }
    };
    emit(acc0, 0); emit(acc1, 1); emit(acc2, 2); emit(acc3, 3);

    // ---- block reduction (reuse tile LDS) ----
    __syncthreads();
    float* red = (float*)tile;
    red[tid] = s; red[256 + tid] = q;
    __syncthreads();
    for (int off = 128; off > 0; off >>= 1) {
        if (tid < off) { red[tid] += red[tid + off]; red[256 + tid] += red[256 + tid + off]; }
        __syncthreads();
    }
    if (tid == 0) {
        const int bid = (blockIdx.z * 8 + blockIdx.y) * 8 + blockIdx.x;
        partials[bid * 2] = red[0];
        partials[bid * 2 + 1] = red[256];
    }
}

__global__ __launch_bounds__(256) void finalize_k(
    const float* __restrict__ partials, float* __restrict__ stats, int stage,
    const float* __restrict__ gamma, const float* __restrict__ beta)
{
    __shared__ double rs[256], rq[256];
    const int tid = threadIdx.x;
    double s = 0.0, q = 0.0;
    for (int i = tid; i < NBLK; i += 256) { s += partials[2 * i]; q += partials[2 * i + 1]; }
    rs[tid] = s; rq[tid] = q;
    __syncthreads();
    for (int off = 128; off > 0; off >>= 1) {
        if (tid < off) { rs[tid] += rs[tid + off]; rq[tid] += rq[tid + off]; }
        __syncthreads();
    }
    if (tid == 0) {
        double mean = rs[0] / (double)NTOT;
        double var = rq[0] / (double)NTOT - mean * mean;
        double scl = (double)gamma[0] / sqrt(var + 1e-5);
        stats[2 * stage] = (float)scl;
        stats[2 * stage + 1] = (float)((double)beta[0] - mean * scl);
    }
}

// out = shrink(n3(t3) + n1(t1), lambd[2]); t3 bf16 (T3BF) or fp32 in io
template <bool T3BF>
__global__ __launch_bounds__(256) void final_k(
    const unsigned short* __restrict__ t1,
    const unsigned short* __restrict__ t3b,
    float* __restrict__ io,
    const float* __restrict__ stats, const float* __restrict__ lambd)
{
    const float s1 = stats[0], h1 = stats[1], s3 = stats[4], h3 = stats[5];
    const float lam = lambd[2];
    const size_t base = ((size_t)blockIdx.x * 256 + threadIdx.x) * 8;

    uint4 u1 = *(const uint4*)(t1 + base);
    float f1[8]; bf8(u1, f1);

    float t3v[8];
    if constexpr (T3BF) {
        uint4 u3 = *(const uint4*)(t3b + base);
        bf8(u3, t3v);
    } else {
        float4 a0 = *(const float4*)(io + base);
        float4 a1 = *(const float4*)(io + base + 4);
        t3v[0]=a0.x; t3v[1]=a0.y; t3v[2]=a0.z; t3v[3]=a0.w;
        t3v[4]=a1.x; t3v[5]=a1.y; t3v[6]=a1.z; t3v[7]=a1.w;
    }

    float r[8];
#pragma unroll
    for (int k = 0; k < 8; k++) {
        float v = __builtin_fmaf(t3v[k], s3, h3) + __builtin_fmaf(f1[k], s1, h1);
        r[k] = shrinkf(v, lam);
    }
    *(float4*)(io + base)     = make_float4(r[0], r[1], r[2], r[3]);
    *(float4*)(io + base + 4) = make_float4(r[4], r[5], r[6], r[7]);
}

extern "C" void kernel_launch(void* const* d_in, const int* in_sizes, int n_in,
                              void* d_out, int out_size, void* d_ws, size_t ws_size,
                              hipStream_t stream)
{
    const float* y     = (const float*)d_in[0];
    const float* wgt   = (const float*)d_in[1];
    const float* bias  = (const float*)d_in[2];
    const float* gamma = (const float*)d_in[3];
    const float* beta  = (const float*)d_in[4];
    const float* lambd = (const float*)d_in[5];
    float* out = (float*)d_out;

    char* ws = (char*)d_ws;
    unsigned short* t1 = (unsigned short*)ws;                    // 33,554,432 B
    unsigned short* t2 = (unsigned short*)(ws + 33554432ull);    // 33,554,432 B
    unsigned short* t3 = (unsigned short*)(ws + 67108864ull);    // 33,554,432 B
    const bool t3bf = (ws_size >= 100696088ull);
    const size_t poff = t3bf ? 100663296ull : 67108864ull;
    float* partials = (float*)(ws + poff);                       // 32,768 B
    float* stats    = (float*)(ws + poff + 32768ull);            // 24 B

    dim3 grid(8, 8, 64), blk(256);
    conv_k<0, true><<<grid, blk, 0, stream>>>(y, nullptr, nullptr, t1, nullptr,
                                              wgt, bias, stats, lambd, partials);
    finalize_k<<<1, blk, 0, stream>>>(partials, stats, 0, gamma, beta);
    conv_k<1, true><<<grid, blk, 0, stream>>>(nullptr, t1, nullptr, t2, nullptr,
                                              wgt, bias, stats, lambd, partials);
    finalize_k<<<1, blk, 0, stream>>>(partials, stats, 1, gamma, beta);
    if (t3bf) {
        conv_k<2, true><<<grid, blk, 0, stream>>>(nullptr, t1, t2, t3, nullptr,
                                                  wgt, bias, stats, lambd, partials);
        finalize_k<<<1, blk, 0, stream>>>(partials, stats, 2, gamma, beta);
        final_k<true><<<8192, blk, 0, stream>>>(t1, t3, out, stats, lambd);
    } else {
        conv_k<2, false><<<grid, blk, 0, stream>>>(nullptr, t1, t2, nullptr, out,
                                                   wgt, bias, stats, lambd, partials);
        finalize_k<<<1, blk, 0, stream>>>(partials, stats, 2, gamma, beta);
        final_k<false><<<8192, blk, 0, stream>>>(t1, nullptr, out, stats, lambd);
    }
}

// Round 7
// 116.617 us; speedup vs baseline: 1.8026x; 1.1592x over previous
//
#include <hip/hip_runtime.h>
#include <math.h>

#define HH 512
#define WW 512
#define NTOT (64u*512u*512u)
#define NBLK 1024
#define TS 128          // output tile edge
#define TROWS 132       // TS + 4 halo rows
#define TCH 18          // 8-wide chunks per row (144 cols: gx in [bx-8, bx+136))
#define TPIT 152        // LDS pitch (bf16): 304 B/row, 16B-aligned
#define NTASK (TROWS*TCH)   // 2376
#define NITER 10            // ceil(NTASK/256)

typedef __attribute__((ext_vector_type(8))) short short8;
typedef __attribute__((ext_vector_type(4))) float f32x4;

__device__ __forceinline__ float fsqrtf(float x) { return __builtin_amdgcn_sqrtf(x); }

__device__ __forceinline__ float shrinkf(float x, float l) {
    float a = x - l, b = x + l;
    return x + 0.5f * (fsqrtf(__builtin_fmaf(a, a, 1.f)) - fsqrtf(__builtin_fmaf(b, b, 1.f)));
}

__device__ __forceinline__ float bf2f(unsigned int u) {
    union { unsigned int i; float f; } cv;
    cv.i = u << 16;
    return cv.f;
}
__device__ __forceinline__ float lo2f(unsigned int p) {
    union { unsigned int i; float f; } cv; cv.i = p << 16; return cv.f;
}
__device__ __forceinline__ float hi2f(unsigned int p) {
    union { unsigned int i; float f; } cv; cv.i = p & 0xffff0000u; return cv.f;
}

__device__ __forceinline__ unsigned short f2bf(float f) {
    union { float f; unsigned int i; } cv;
    cv.f = f;
    unsigned int i = cv.i;
    unsigned int r = (i + 0x7fffu + ((i >> 16) & 1u)) >> 16;  // RNE
    return (unsigned short)r;
}

// v_cvt_pk_bf16_f32: dst = bf16(lo) | (bf16(hi) << 16)
__device__ __forceinline__ unsigned int cvtpk(float lo, float hi) {
    unsigned int r;
    asm("v_cvt_pk_bf16_f32 %0, %1, %2" : "=v"(r) : "v"(lo), "v"(hi));
    return r;
}

__device__ __forceinline__ void bf8(uint4 u, float* f) {
    f[0] = bf2f(u.x & 0xffffu); f[1] = bf2f(u.x >> 16);
    f[2] = bf2f(u.y & 0xffffu); f[3] = bf2f(u.y >> 16);
    f[4] = bf2f(u.z & 0xffffu); f[5] = bf2f(u.z >> 16);
    f[6] = bf2f(u.w & 0xffffu); f[7] = bf2f(u.w >> 16);
}

// MFMA conv (Toeplitz): out[ct] += sum_ky A_ky(16x32) x B_ky(32x16)
//   A_ky[m][k] = tile[row0+m+ky][ct*16 + k]  (tile col t <-> gx = bx + t - 8)
//   B_ky[k][n] = w[ky][k-n-6] if 0 <= k-n-6 <= 4 else 0
// MODE 0: y (fp32) identity -> t1 bf16
// MODE 1: t1, shrink(n1(t1), l0) -> t2 bf16
// MODE 2: t1,t2, shrink(n2+n1, l1) -> t3 bf16 (OBF) / fp32 (!OBF)
template <int MODE, bool OBF>
__global__ __launch_bounds__(256, 3) void conv_k(
    const float* __restrict__ yin,
    const unsigned short* __restrict__ t1,
    const unsigned short* __restrict__ t2,
    unsigned short* __restrict__ outbf,
    float* __restrict__ outf32,
    const float* __restrict__ wgt,
    const float* __restrict__ bias,
    const float* __restrict__ stats,
    const float* __restrict__ lambd,
    float* __restrict__ partials)
{
    __shared__ unsigned short tile[TROWS * TPIT];
    __shared__ uint4 btab[5 * 64];

    const int tid = threadIdx.x;
    const int by = blockIdx.y * TS;
    const int bx = blockIdx.x * TS;
    const size_t ibase = (size_t)blockIdx.z * (HH * WW);

    float s1 = 0.f, h1 = 0.f, s2v = 0.f, h2 = 0.f, lam = 0.f;
    if constexpr (MODE == 1) { s1 = stats[0]; h1 = stats[1]; lam = lambd[0]; }
    if constexpr (MODE == 2) {
        s1 = stats[0]; h1 = stats[1]; s2v = stats[2]; h2 = stats[3]; lam = lambd[1];
    }

    // ---- B-fragment table (wave 0): lane holds B[k=(l>>4)*8+j][n=l&15] ----
    if (tid < 64) {
        float wloc[25];
#pragma unroll
        for (int i = 0; i < 25; i++) wloc[i] = wgt[i];
        const int sPos = (tid & 15) + 6 - (tid >> 4) * 8;   // j = sPos + kx
#pragma unroll
        for (int ky = 0; ky < 5; ky++) {
            unsigned short ev[8];
#pragma unroll
            for (int j = 0; j < 8; j++) {
                float v = 0.f;
#pragma unroll
                for (int t = 0; t < 5; t++)
                    if (j - sPos == t) v = wloc[ky * 5 + t];
                ev[j] = f2bf(v);
            }
            btab[ky * 64 + tid] = make_uint4(
                ev[0] | ((unsigned)ev[1] << 16), ev[2] | ((unsigned)ev[3] << 16),
                ev[4] | ((unsigned)ev[5] << 16), ev[6] | ((unsigned)ev[7] << 16));
        }
    }

    // ---- staging: fused loop with 1-ahead prefetch (2 loads in flight) ----
    uint4 curA = make_uint4(0u,0u,0u,0u), curB = make_uint4(0u,0u,0u,0u);
    {
        const int task = tid;                    // first task
        const int row = task / TCH;
        const int ch  = task - row * TCH;
        const int gy  = by + row - 2;
        const int gx0 = bx + ch * 8 - 8;
        if (gy >= 0 && gy < HH && gx0 >= 0 && gx0 <= WW - 8) {
            const size_t g = ibase + (size_t)gy * WW + gx0;
            if constexpr (MODE == 0) {
                curA = *(const uint4*)(yin + g);
                curB = *(const uint4*)(yin + g + 4);
            } else if constexpr (MODE == 1) {
                curA = *(const uint4*)(t1 + g);
            } else {
                curA = *(const uint4*)(t1 + g);
                curB = *(const uint4*)(t2 + g);
            }
        }
    }
#pragma unroll
    for (int t = 0; t < NITER; t++) {
        // prefetch next task's data
        uint4 nxtA = make_uint4(0u,0u,0u,0u), nxtB = make_uint4(0u,0u,0u,0u);
        if (t + 1 < NITER) {
            const int ntsk = tid + (t + 1) * 256;
            const int row = ntsk / TCH;
            const int ch  = ntsk - row * TCH;
            const int gy  = by + row - 2;
            const int gx0 = bx + ch * 8 - 8;
            if (ntsk < NTASK && gy >= 0 && gy < HH && gx0 >= 0 && gx0 <= WW - 8) {
                const size_t g = ibase + (size_t)gy * WW + gx0;
                if constexpr (MODE == 0) {
                    nxtA = *(const uint4*)(yin + g);
                    nxtB = *(const uint4*)(yin + g + 4);
                } else if constexpr (MODE == 1) {
                    nxtA = *(const uint4*)(t1 + g);
                } else {
                    nxtA = *(const uint4*)(t1 + g);
                    nxtB = *(const uint4*)(t2 + g);
                }
            }
        }
        // transform current task and write LDS (OOB chunks stay literal zero)
        const int task = tid + t * 256;
        if (task < NTASK) {
            const int row = task / TCH;
            const int ch  = task - row * TCH;
            uint4 pk = make_uint4(0u,0u,0u,0u);
            if constexpr (MODE == 0) {
                const float4 a = *(const float4*)&curA;
                const float4 b = *(const float4*)&curB;
                pk.x = cvtpk(a.x, a.y); pk.y = cvtpk(a.z, a.w);
                pk.z = cvtpk(b.x, b.y); pk.w = cvtpk(b.z, b.w);
            } else if constexpr (MODE == 1) {
                float f1[8]; bf8(curA, f1);
                float v[8];
#pragma unroll
                for (int k = 0; k < 8; k++)
                    v[k] = shrinkf(__builtin_fmaf(f1[k], s1, h1), lam);
                pk.x = cvtpk(v[0], v[1]); pk.y = cvtpk(v[2], v[3]);
                pk.z = cvtpk(v[4], v[5]); pk.w = cvtpk(v[6], v[7]);
            } else {
                float f1[8], f2[8]; bf8(curA, f1); bf8(curB, f2);
                float v[8];
#pragma unroll
                for (int k = 0; k < 8; k++) {
                    float x = __builtin_fmaf(f2[k], s2v, h2)
                            + __builtin_fmaf(f1[k], s1, h1);
                    v[k] = shrinkf(x, lam);
                }
                pk.x = cvtpk(v[0], v[1]); pk.y = cvtpk(v[2], v[3]);
                pk.z = cvtpk(v[4], v[5]); pk.w = cvtpk(v[6], v[7]);
            }
            // zero result for OOB chunks: transform ran on zeros, but we must
            // store literal zero (reference pads post-transform input with 0)
            const int gy  = by + row - 2;
            const int gx0 = bx + ch * 8 - 8;
            if (!(gy >= 0 && gy < HH && gx0 >= 0 && gx0 <= WW - 8))
                pk = make_uint4(0u,0u,0u,0u);
            *(uint4*)&tile[row * TPIT + ch * 8] = pk;
        }
        curA = nxtA; curB = nxtB;
    }

    const float b0 = bias[0];
    __syncthreads();

    // ---- MFMA phase: wave wv owns 32 output rows x 128 cols ----
    const int wv = tid >> 6;
    const int lane = tid & 63;
    const int lm = lane & 15;
    const int kb = lane >> 4;
    const int r0w = wv * 32;

    f32x4 acc[2][8];
#pragma unroll
    for (int st = 0; st < 2; st++)
#pragma unroll
        for (int ct = 0; ct < 8; ct++)
            acc[st][ct] = (f32x4){0.f, 0.f, 0.f, 0.f};

#pragma unroll
    for (int ky = 0; ky < 5; ky++) {
        const short8 bfr = *(const short8*)&btab[ky * 64 + lane];
#pragma unroll
        for (int st = 0; st < 2; st++) {
            const unsigned short* ab = &tile[(r0w + st * 16 + lm + ky) * TPIT + kb * 8];
#pragma unroll
            for (int ct = 0; ct < 8; ct++) {
                short8 a = *(const short8*)(ab + ct * 16);
                acc[st][ct] = __builtin_amdgcn_mfma_f32_16x16x32_bf16(a, bfr, acc[st][ct], 0, 0, 0);
            }
        }
    }

    // ---- epilogue: lane holds rows kb*4+e, col lm of each 16x16 tile ----
    float s = 0.f, q = 0.f;
#pragma unroll
    for (int st = 0; st < 2; st++) {
#pragma unroll
        for (int ct = 0; ct < 8; ct++) {
            const f32x4 a = acc[st][ct];
            const int grow0 = by + r0w + st * 16 + kb * 4;
            const size_t base = ibase + (size_t)grow0 * WW + bx + ct * 16 + lm;
            if constexpr (OBF) {
                unsigned p01 = cvtpk(a[0] + b0, a[1] + b0);
                unsigned p23 = cvtpk(a[2] + b0, a[3] + b0);
                outbf[base]          = (unsigned short)(p01 & 0xffffu);
                outbf[base + WW]     = (unsigned short)(p01 >> 16);
                outbf[base + 2 * WW] = (unsigned short)(p23 & 0xffffu);
                outbf[base + 3 * WW] = (unsigned short)(p23 >> 16);
                float fr0 = lo2f(p01), fr1 = hi2f(p01), fr2 = lo2f(p23), fr3 = hi2f(p23);
                s += fr0 + fr1 + fr2 + fr3;
                q = __builtin_fmaf(fr0, fr0, __builtin_fmaf(fr1, fr1,
                    __builtin_fmaf(fr2, fr2, __builtin_fmaf(fr3, fr3, q))));
            } else {
                float f0 = a[0] + b0, f1v = a[1] + b0, f2v = a[2] + b0, f3v = a[3] + b0;
                outf32[base]          = f0;
                outf32[base + WW]     = f1v;
                outf32[base + 2 * WW] = f2v;
                outf32[base + 3 * WW] = f3v;
                s += f0 + f1v + f2v + f3v;
                q = __builtin_fmaf(f0, f0, __builtin_fmaf(f1v, f1v,
                    __builtin_fmaf(f2v, f2v, __builtin_fmaf(f3v, f3v, q))));
            }
        }
    }

    // ---- block reduction (LDS tree, reuse tile) ----
    __syncthreads();
    float* red = (float*)tile;
    red[tid] = s; red[256 + tid] = q;
    __syncthreads();
    for (int off = 128; off > 0; off >>= 1) {
        if (tid < off) { red[tid] += red[tid + off]; red[256 + tid] += red[256 + tid + off]; }
        __syncthreads();
    }
    if (tid == 0) {
        const int bid = (blockIdx.z * 4 + blockIdx.y) * 4 + blockIdx.x;
        partials[bid * 2] = red[0];
        partials[bid * 2 + 1] = red[256];
    }
}

__global__ __launch_bounds__(256) void finalize_k(
    const float* __restrict__ partials, float* __restrict__ stats, int stage,
    const float* __restrict__ gamma, const float* __restrict__ beta)
{
    __shared__ double rs[256], rq[256];
    const int tid = threadIdx.x;
    double s = 0.0, q = 0.0;
    for (int i = tid; i < NBLK; i += 256) { s += partials[2 * i]; q += partials[2 * i + 1]; }
    rs[tid] = s; rq[tid] = q;
    __syncthreads();
    for (int off = 128; off > 0; off >>= 1) {
        if (tid < off) { rs[tid] += rs[tid + off]; rq[tid] += rq[tid + off]; }
        __syncthreads();
    }
    if (tid == 0) {
        double mean = rs[0] / (double)NTOT;
        double var = rq[0] / (double)NTOT - mean * mean;
        double scl = (double)gamma[0] / sqrt(var + 1e-5);
        stats[2 * stage] = (float)scl;
        stats[2 * stage + 1] = (float)((double)beta[0] - mean * scl);
    }
}

// out = shrink(n3(t3) + n1(t1), lambd[2]); t3 bf16 (T3BF) or fp32 in io
template <bool T3BF>
__global__ __launch_bounds__(256) void final_k(
    const unsigned short* __restrict__ t1,
    const unsigned short* __restrict__ t3b,
    float* __restrict__ io,
    const float* __restrict__ stats, const float* __restrict__ lambd)
{
    const float s1 = stats[0], h1 = stats[1], s3 = stats[4], h3 = stats[5];
    const float lam = lambd[2];
    const size_t base = ((size_t)blockIdx.x * 256 + threadIdx.x) * 8;

    uint4 u1 = *(const uint4*)(t1 + base);
    float f1[8]; bf8(u1, f1);

    float t3v[8];
    if constexpr (T3BF) {
        uint4 u3 = *(const uint4*)(t3b + base);
        bf8(u3, t3v);
    } else {
        float4 a0 = *(const float4*)(io + base);
        float4 a1 = *(const float4*)(io + base + 4);
        t3v[0]=a0.x; t3v[1]=a0.y; t3v[2]=a0.z; t3v[3]=a0.w;
        t3v[4]=a1.x; t3v[5]=a1.y; t3v[6]=a1.z; t3v[7]=a1.w;
    }

    float r[8];
#pragma unroll
    for (int k = 0; k < 8; k++) {
        float v = __builtin_fmaf(t3v[k], s3, h3) + __builtin_fmaf(f1[k], s1, h1);
        r[k] = shrinkf(v, lam);
    }
    *(float4*)(io + base)     = make_float4(r[0], r[1], r[2], r[3]);
    *(float4*)(io + base + 4) = make_float4(r[4], r[5], r[6], r[7]);
}

extern "C" void kernel_launch(void* const* d_in, const int* in_sizes, int n_in,
                              void* d_out, int out_size, void* d_ws, size_t ws_size,
                              hipStream_t stream)
{
    const float* y     = (const float*)d_in[0];
    const float* wgt   = (const float*)d_in[1];
    const float* bias  = (const float*)d_in[2];
    const float* gamma = (const float*)d_in[3];
    const float* beta  = (const float*)d_in[4];
    const float* lambd = (const float*)d_in[5];
    float* out = (float*)d_out;

    char* ws = (char*)d_ws;
    unsigned short* t1 = (unsigned short*)ws;                    // 33,554,432 B
    unsigned short* t2 = (unsigned short*)(ws + 33554432ull);    // 33,554,432 B
    unsigned short* t3 = (unsigned short*)(ws + 67108864ull);    // 33,554,432 B
    const bool t3bf = (ws_size >= 100696088ull);
    const size_t poff = t3bf ? 100663296ull : 67108864ull;
    float* partials = (float*)(ws + poff);                       // 8,192 B used
    float* stats    = (float*)(ws + poff + 32768ull);            // 24 B

    dim3 grid(4, 4, 64), blk(256);
    conv_k<0, true><<<grid, blk, 0, stream>>>(y, nullptr, nullptr, t1, nullptr,
                                              wgt, bias, stats, lambd, partials);
    finalize_k<<<1, blk, 0, stream>>>(partials, stats, 0, gamma, beta);
    conv_k<1, true><<<grid, blk, 0, stream>>>(nullptr, t1, nullptr, t2, nullptr,
                                              wgt, bias, stats, lambd, partials);
    finalize_k<<<1, blk, 0, stream>>>(partials, stats, 1, gamma, beta);
    if (t3bf) {
        conv_k<2, true><<<grid, blk, 0, stream>>>(nullptr, t1, t2, t3, nullptr,
                                                  wgt, bias, stats, lambd, partials);
        finalize_k<<<1, blk, 0, stream>>>(partials, stats, 2, gamma, beta);
        final_k<true><<<8192, blk, 0, stream>>>(t1, t3, out, stats, lambd);
    } else {
        conv_k<2, false><<<grid, blk, 0, stream>>>(nullptr, t1, t2, nullptr, out,
                                                   wgt, bias, stats, lambd, partials);
        finalize_k<<<1, blk, 0, stream>>>(partials, stats, 2, gamma, beta);
        final_k<false><<<8192, blk, 0, stream>>>(t1, nullptr, out, stats, lambd);
    }
}

// Round 8
// 108.626 us; speedup vs baseline: 1.9352x; 1.0736x over previous
//
#include <hip/hip_runtime.h>
#include <math.h>

#define HH 512
#define WW 512
#define NTOT (64u*512u*512u)
#define NBLK 1024
#define TS 128          // output tile edge
#define TROWS 132       // TS + 4 halo rows
#define TCH 18          // 8-wide chunks per row (144 cols: gx in [bx-8, bx+136))
#define TPIT 152        // LDS pitch (bf16): 304 B/row, 16B-aligned
#define NTASK (TROWS*TCH)   // 2376
#define NITER 10            // ceil(NTASK/256)

typedef __attribute__((ext_vector_type(8))) short short8;
typedef __attribute__((ext_vector_type(4))) float f32x4;

__device__ __forceinline__ float fsqrtf(float x) { return __builtin_amdgcn_sqrtf(x); }

__device__ __forceinline__ float shrinkf(float x, float l) {
    float a = x - l, b = x + l;
    return x + 0.5f * (fsqrtf(__builtin_fmaf(a, a, 1.f)) - fsqrtf(__builtin_fmaf(b, b, 1.f)));
}

__device__ __forceinline__ float bf2f(unsigned int u) {
    union { unsigned int i; float f; } cv;
    cv.i = u << 16;
    return cv.f;
}
__device__ __forceinline__ float lo2f(unsigned int p) {
    union { unsigned int i; float f; } cv; cv.i = p << 16; return cv.f;
}
__device__ __forceinline__ float hi2f(unsigned int p) {
    union { unsigned int i; float f; } cv; cv.i = p & 0xffff0000u; return cv.f;
}

// v_cvt_pk_bf16_f32 (RNE): dst = bf16(lo) | (bf16(hi) << 16)
__device__ __forceinline__ unsigned int cvtpk(float lo, float hi) {
    unsigned int r;
    asm("v_cvt_pk_bf16_f32 %0, %1, %2" : "=v"(r) : "v"(lo), "v"(hi));
    return r;
}

__device__ __forceinline__ void bf8(uint4 u, float* f) {
    f[0] = bf2f(u.x & 0xffffu); f[1] = bf2f(u.x >> 16);
    f[2] = bf2f(u.y & 0xffffu); f[3] = bf2f(u.y >> 16);
    f[4] = bf2f(u.z & 0xffffu); f[5] = bf2f(u.z >> 16);
    f[6] = bf2f(u.w & 0xffffu); f[7] = bf2f(u.w >> 16);
}

// MFMA conv (Toeplitz): out[ct] += sum_ky A_ky(16x32) x B_ky(32x16)
//   A_ky[m][k] = tile[row0+m+ky][ct*16 + k]  (tile col t <-> gx = bx + t - 8)
//   B_ky[k][n] = w[ky][k-n-6] if 0 <= k-n-6 <= 4 else 0
// MODE 0: y (fp32) identity -> t1 bf16
// MODE 1: t1, shrink(n1(t1), l0) -> t2 bf16
// MODE 2: t1,t2, shrink(n2+n1, l1) -> t3 bf16 (OBF) / fp32 (!OBF)
template <int MODE, bool OBF>
__global__ __launch_bounds__(256, 4) void conv_k(
    const float* __restrict__ yin,
    const unsigned short* __restrict__ t1,
    const unsigned short* __restrict__ t2,
    unsigned short* __restrict__ outbf,
    float* __restrict__ outf32,
    const float* __restrict__ wgt,
    const float* __restrict__ bias,
    const float* __restrict__ stats,
    const float* __restrict__ lambd,
    float* __restrict__ partials)
{
    __shared__ unsigned short tile[TROWS * TPIT];   // 40,128 B -> 4 blocks/CU

    const int tid = threadIdx.x;
    const int by = blockIdx.y * TS;
    const int bx = blockIdx.x * TS;
    const size_t ibase = (size_t)blockIdx.z * (HH * WW);

    float s1 = 0.f, h1 = 0.f, s2v = 0.f, h2 = 0.f, lam = 0.f;
    if constexpr (MODE == 1) { s1 = stats[0]; h1 = stats[1]; lam = lambd[0]; }
    if constexpr (MODE == 2) {
        s1 = stats[0]; h1 = stats[1]; s2v = stats[2]; h2 = stats[3]; lam = lambd[1];
    }

    // uniform weights -> SGPRs
    float wloc[25];
#pragma unroll
    for (int i = 0; i < 25; i++) wloc[i] = wgt[i];

    // ---- lane-local B fragments (no LDS): lane holds B[k=kb*8+j][n=lm] ----
    const int lane = tid & 63;
    const int lm = lane & 15;
    const int kb = lane >> 4;
    const int basei = kb * 8 - lm - 6;   // idx = basei + j, valid 0..4
    short8 bfr[5];
#pragma unroll
    for (int ky = 0; ky < 5; ky++) {
        unsigned pkw[4];
#pragma unroll
        for (int jj = 0; jj < 4; jj++) {
            float v0 = 0.f, v1 = 0.f;
            const int i0 = basei + 2 * jj, i1 = i0 + 1;
#pragma unroll
            for (int t = 0; t < 5; t++) {
                if (i0 == t) v0 = wloc[ky * 5 + t];
                if (i1 == t) v1 = wloc[ky * 5 + t];
            }
            pkw[jj] = cvtpk(v0, v1);
        }
        union { unsigned u[4]; short8 s; } cv;
        cv.u[0] = pkw[0]; cv.u[1] = pkw[1]; cv.u[2] = pkw[2]; cv.u[3] = pkw[3];
        bfr[ky] = cv.s;
    }

    // ---- staging: fused loop with 1-ahead prefetch (2 loads in flight) ----
    uint4 curA = make_uint4(0u,0u,0u,0u), curB = make_uint4(0u,0u,0u,0u);
    {
        const int task = tid;                    // first task
        const int row = task / TCH;
        const int ch  = task - row * TCH;
        const int gy  = by + row - 2;
        const int gx0 = bx + ch * 8 - 8;
        if (gy >= 0 && gy < HH && gx0 >= 0 && gx0 <= WW - 8) {
            const size_t g = ibase + (size_t)gy * WW + gx0;
            if constexpr (MODE == 0) {
                curA = *(const uint4*)(yin + g);
                curB = *(const uint4*)(yin + g + 4);
            } else if constexpr (MODE == 1) {
                curA = *(const uint4*)(t1 + g);
            } else {
                curA = *(const uint4*)(t1 + g);
                curB = *(const uint4*)(t2 + g);
            }
        }
    }
#pragma unroll
    for (int t = 0; t < NITER; t++) {
        // prefetch next task's data
        uint4 nxtA = make_uint4(0u,0u,0u,0u), nxtB = make_uint4(0u,0u,0u,0u);
        if (t + 1 < NITER) {
            const int ntsk = tid + (t + 1) * 256;
            const int row = ntsk / TCH;
            const int ch  = ntsk - row * TCH;
            const int gy  = by + row - 2;
            const int gx0 = bx + ch * 8 - 8;
            if (ntsk < NTASK && gy >= 0 && gy < HH && gx0 >= 0 && gx0 <= WW - 8) {
                const size_t g = ibase + (size_t)gy * WW + gx0;
                if constexpr (MODE == 0) {
                    nxtA = *(const uint4*)(yin + g);
                    nxtB = *(const uint4*)(yin + g + 4);
                } else if constexpr (MODE == 1) {
                    nxtA = *(const uint4*)(t1 + g);
                } else {
                    nxtA = *(const uint4*)(t1 + g);
                    nxtB = *(const uint4*)(t2 + g);
                }
            }
        }
        // transform current task and write LDS (OOB chunks store literal zero)
        const int task = tid + t * 256;
        if (task < NTASK) {
            const int row = task / TCH;
            const int ch  = task - row * TCH;
            uint4 pk = make_uint4(0u,0u,0u,0u);
            if constexpr (MODE == 0) {
                const float4 a = *(const float4*)&curA;
                const float4 b = *(const float4*)&curB;
                pk.x = cvtpk(a.x, a.y); pk.y = cvtpk(a.z, a.w);
                pk.z = cvtpk(b.x, b.y); pk.w = cvtpk(b.z, b.w);
            } else if constexpr (MODE == 1) {
                float f1[8]; bf8(curA, f1);
                float v[8];
#pragma unroll
                for (int k = 0; k < 8; k++)
                    v[k] = shrinkf(__builtin_fmaf(f1[k], s1, h1), lam);
                pk.x = cvtpk(v[0], v[1]); pk.y = cvtpk(v[2], v[3]);
                pk.z = cvtpk(v[4], v[5]); pk.w = cvtpk(v[6], v[7]);
            } else {
                float f1[8], f2[8]; bf8(curA, f1); bf8(curB, f2);
                float v[8];
#pragma unroll
                for (int k = 0; k < 8; k++) {
                    float x = __builtin_fmaf(f2[k], s2v, h2)
                            + __builtin_fmaf(f1[k], s1, h1);
                    v[k] = shrinkf(x, lam);
                }
                pk.x = cvtpk(v[0], v[1]); pk.y = cvtpk(v[2], v[3]);
                pk.z = cvtpk(v[4], v[5]); pk.w = cvtpk(v[6], v[7]);
            }
            // OOB chunk: transform ran on zeros, but reference zero-pads the
            // post-transform conv input -> store literal zero
            const int gy  = by + row - 2;
            const int gx0 = bx + ch * 8 - 8;
            if (!(gy >= 0 && gy < HH && gx0 >= 0 && gx0 <= WW - 8))
                pk = make_uint4(0u,0u,0u,0u);
            *(uint4*)&tile[row * TPIT + ch * 8] = pk;
        }
        curA = nxtA; curB = nxtB;
    }

    const float b0 = bias[0];
    __syncthreads();

    // ---- MFMA phase: wave wv owns 32 output rows x 128 cols ----
    const int wv = tid >> 6;
    const int r0w = wv * 32;

    f32x4 acc[2][8];
#pragma unroll
    for (int st = 0; st < 2; st++)
#pragma unroll
        for (int ct = 0; ct < 8; ct++)
            acc[st][ct] = (f32x4){0.f, 0.f, 0.f, 0.f};

#pragma unroll
    for (int ky = 0; ky < 5; ky++) {
        const short8 b = bfr[ky];
#pragma unroll
        for (int st = 0; st < 2; st++) {
            const unsigned short* ab = &tile[(r0w + st * 16 + lm + ky) * TPIT + kb * 8];
#pragma unroll
            for (int ct = 0; ct < 8; ct++) {
                short8 a = *(const short8*)(ab + ct * 16);
                acc[st][ct] = __builtin_amdgcn_mfma_f32_16x16x32_bf16(a, b, acc[st][ct], 0, 0, 0);
            }
        }
    }

    // ---- epilogue: lane holds rows kb*4+e, col lm of each 16x16 tile ----
    float s = 0.f, q = 0.f;
#pragma unroll
    for (int st = 0; st < 2; st++) {
#pragma unroll
        for (int ct = 0; ct < 8; ct++) {
            const f32x4 a = acc[st][ct];
            const int grow0 = by + r0w + st * 16 + kb * 4;
            const size_t base = ibase + (size_t)grow0 * WW + bx + ct * 16 + lm;
            if constexpr (OBF) {
                unsigned p01 = cvtpk(a[0] + b0, a[1] + b0);
                unsigned p23 = cvtpk(a[2] + b0, a[3] + b0);
                outbf[base]          = (unsigned short)(p01 & 0xffffu);
                outbf[base + WW]     = (unsigned short)(p01 >> 16);
                outbf[base + 2 * WW] = (unsigned short)(p23 & 0xffffu);
                outbf[base + 3 * WW] = (unsigned short)(p23 >> 16);
                float fr0 = lo2f(p01), fr1 = hi2f(p01), fr2 = lo2f(p23), fr3 = hi2f(p23);
                s += fr0 + fr1 + fr2 + fr3;
                q = __builtin_fmaf(fr0, fr0, __builtin_fmaf(fr1, fr1,
                    __builtin_fmaf(fr2, fr2, __builtin_fmaf(fr3, fr3, q))));
            } else {
                float f0 = a[0] + b0, f1v = a[1] + b0, f2v = a[2] + b0, f3v = a[3] + b0;
                outf32[base]          = f0;
                outf32[base + WW]     = f1v;
                outf32[base + 2 * WW] = f2v;
                outf32[base + 3 * WW] = f3v;
                s += f0 + f1v + f2v + f3v;
                q = __builtin_fmaf(f0, f0, __builtin_fmaf(f1v, f1v,
                    __builtin_fmaf(f2v, f2v, __builtin_fmaf(f3v, f3v, q))));
            }
        }
    }

    // ---- block reduction (LDS tree, reuse tile) ----
    __syncthreads();
    float* red = (float*)tile;
    red[tid] = s; red[256 + tid] = q;
    __syncthreads();
    for (int off = 128; off > 0; off >>= 1) {
        if (tid < off) { red[tid] += red[tid + off]; red[256 + tid] += red[256 + tid + off]; }
        __syncthreads();
    }
    if (tid == 0) {
        const int bid = (blockIdx.z * 4 + blockIdx.y) * 4 + blockIdx.x;
        partials[bid * 2] = red[0];
        partials[bid * 2 + 1] = red[256];
    }
}

__global__ __launch_bounds__(256) void finalize_k(
    const float* __restrict__ partials, float* __restrict__ stats, int stage,
    const float* __restrict__ gamma, const float* __restrict__ beta)
{
    __shared__ double rs[256], rq[256];
    const int tid = threadIdx.x;
    double s = 0.0, q = 0.0;
    for (int i = tid; i < NBLK; i += 256) { s += partials[2 * i]; q += partials[2 * i + 1]; }
    rs[tid] = s; rq[tid] = q;
    __syncthreads();
    for (int off = 128; off > 0; off >>= 1) {
        if (tid < off) { rs[tid] += rs[tid + off]; rq[tid] += rq[tid + off]; }
        __syncthreads();
    }
    if (tid == 0) {
        double mean = rs[0] / (double)NTOT;
        double var = rq[0] / (double)NTOT - mean * mean;
        double scl = (double)gamma[0] / sqrt(var + 1e-5);
        stats[2 * stage] = (float)scl;
        stats[2 * stage + 1] = (float)((double)beta[0] - mean * scl);
    }
}

// out = shrink(n3(t3) + n1(t1), lambd[2]); t3 bf16 (T3BF) or fp32 in io
template <bool T3BF>
__global__ __launch_bounds__(256) void final_k(
    const unsigned short* __restrict__ t1,
    const unsigned short* __restrict__ t3b,
    float* __restrict__ io,
    const float* __restrict__ stats, const float* __restrict__ lambd)
{
    const float s1 = stats[0], h1 = stats[1], s3 = stats[4], h3 = stats[5];
    const float lam = lambd[2];
    const size_t base = ((size_t)blockIdx.x * 256 + threadIdx.x) * 8;

    uint4 u1 = *(const uint4*)(t1 + base);
    float f1[8]; bf8(u1, f1);

    float t3v[8];
    if constexpr (T3BF) {
        uint4 u3 = *(const uint4*)(t3b + base);
        bf8(u3, t3v);
    } else {
        float4 a0 = *(const float4*)(io + base);
        float4 a1 = *(const float4*)(io + base + 4);
        t3v[0]=a0.x; t3v[1]=a0.y; t3v[2]=a0.z; t3v[3]=a0.w;
        t3v[4]=a1.x; t3v[5]=a1.y; t3v[6]=a1.z; t3v[7]=a1.w;
    }

    float r[8];
#pragma unroll
    for (int k = 0; k < 8; k++) {
        float v = __builtin_fmaf(t3v[k], s3, h3) + __builtin_fmaf(f1[k], s1, h1);
        r[k] = shrinkf(v, lam);
    }
    *(float4*)(io + base)     = make_float4(r[0], r[1], r[2], r[3]);
    *(float4*)(io + base + 4) = make_float4(r[4], r[5], r[6], r[7]);
}

extern "C" void kernel_launch(void* const* d_in, const int* in_sizes, int n_in,
                              void* d_out, int out_size, void* d_ws, size_t ws_size,
                              hipStream_t stream)
{
    const float* y     = (const float*)d_in[0];
    const float* wgt   = (const float*)d_in[1];
    const float* bias  = (const float*)d_in[2];
    const float* gamma = (const float*)d_in[3];
    const float* beta  = (const float*)d_in[4];
    const float* lambd = (const float*)d_in[5];
    float* out = (float*)d_out;

    char* ws = (char*)d_ws;
    unsigned short* t1 = (unsigned short*)ws;                    // 33,554,432 B
    unsigned short* t2 = (unsigned short*)(ws + 33554432ull);    // 33,554,432 B
    unsigned short* t3 = (unsigned short*)(ws + 67108864ull);    // 33,554,432 B
    const bool t3bf = (ws_size >= 100696088ull);
    const size_t poff = t3bf ? 100663296ull : 67108864ull;
    float* partials = (float*)(ws + poff);                       // 8,192 B used
    float* stats    = (float*)(ws + poff + 32768ull);            // 24 B

    dim3 grid(4, 4, 64), blk(256);
    conv_k<0, true><<<grid, blk, 0, stream>>>(y, nullptr, nullptr, t1, nullptr,
                                              wgt, bias, stats, lambd, partials);
    finalize_k<<<1, blk, 0, stream>>>(partials, stats, 0, gamma, beta);
    conv_k<1, true><<<grid, blk, 0, stream>>>(nullptr, t1, nullptr, t2, nullptr,
                                              wgt, bias, stats, lambd, partials);
    finalize_k<<<1, blk, 0, stream>>>(partials, stats, 1, gamma, beta);
    if (t3bf) {
        conv_k<2, true><<<grid, blk, 0, stream>>>(nullptr, t1, t2, t3, nullptr,
                                                  wgt, bias, stats, lambd, partials);
        finalize_k<<<1, blk, 0, stream>>>(partials, stats, 2, gamma, beta);
        final_k<true><<<8192, blk, 0, stream>>>(t1, t3, out, stats, lambd);
    } else {
        conv_k<2, false><<<grid, blk, 0, stream>>>(nullptr, t1, t2, nullptr, out,
                                                   wgt, bias, stats, lambd, partials);
        finalize_k<<<1, blk, 0, stream>>>(partials, stats, 2, gamma, beta);
        final_k<false><<<8192, blk, 0, stream>>>(t1, nullptr, out, stats, lambd);
    }
}